// Round 1
// baseline (398.467 us; speedup 1.0000x reference)
//
#include <hip/hip_runtime.h>
#include <hip/hip_bf16.h>
#include <cstdint>
#include <cstddef>

// Problem constants
#define BATCH 2
#define TDIM 2048
#define CDIM 1024
#define HN 16
#define DKD 64

typedef __attribute__((ext_vector_type(8))) short s8v;   // 8 bf16 (4 VGPR)
typedef __attribute__((ext_vector_type(4))) short s4v;
typedef __attribute__((ext_vector_type(4))) float f4v;   // MFMA accum

__device__ __forceinline__ short f2bf(float f) {
  unsigned u = __float_as_uint(f);
  unsigned r = u + 0x7fffu + ((u >> 16) & 1u);  // round-nearest-even
  return (short)(r >> 16);
}

#define GLDS16(g, l)                                                         \
  __builtin_amdgcn_global_load_lds(                                          \
      (const __attribute__((address_space(1))) unsigned*)(g),                \
      (__attribute__((address_space(3))) unsigned*)(l), 16, 0, 0)

// ---------------- conversions ----------------
__global__ void cvt4(const float* __restrict__ s, short* __restrict__ d, int n) {
  int i = (blockIdx.x * 256 + threadIdx.x) * 4;
  if (i >= n) return;
  const float4 v = *(const float4*)(s + i);
  s4v o;
  o[0] = f2bf(v.x); o[1] = f2bf(v.y); o[2] = f2bf(v.z); o[3] = f2bf(v.w);
  *(s4v*)(d + i) = o;
}

// w2 (64 x 2048) fp32 -> w2t (2048 x 64) bf16
__global__ void w2_transpose(const float* __restrict__ s, short* __restrict__ d) {
  __shared__ float tile[64][65];
  int k0 = blockIdx.x * 64;
  for (int i = threadIdx.x; i < 64 * 64; i += 256) {
    int r = i >> 6, c = i & 63;
    tile[r][c] = s[(size_t)r * 2048 + k0 + c];
  }
  __syncthreads();
  for (int i = threadIdx.x; i < 64 * 64; i += 256) {
    int kk = i >> 6, dd = i & 63;
    d[(size_t)(k0 + kk) * 64 + dd] = f2bf(tile[dd][kk]);
  }
}

// ---------------- GEMM (A row-major MxK, B row-major NxK i.e. B^T input) ----
// MODE 0: N=2048 fused epilogue -> relu+bias into R[(b,h),t,d], bias into Vt[(b,h),d,t]
// MODE 1: N=1024 bias epilogue -> fp32 out
template <int MODE>
__global__ __launch_bounds__(256) void gemm_bt(
    const short* __restrict__ A, const short* __restrict__ Bw,
    const float* __restrict__ bias0, const float* __restrict__ bias1,
    short* __restrict__ out0, short* __restrict__ out1,
    float* __restrict__ outf, int M, int N, int K) {
  __shared__ __align__(16) short As[128 * 32];
  __shared__ __align__(16) short Bs[128 * 32];
  const int tid = threadIdx.x;
  const int w = tid >> 6, lane = tid & 63, lg = lane >> 4, lc = lane & 15;
  const int m0 = blockIdx.y * 128, n0 = blockIdx.x * 128;
  const int wr = w >> 1, wc = w & 1;

  f4v acc[4][4];
#pragma unroll
  for (int i = 0; i < 4; i++)
#pragma unroll
    for (int j = 0; j < 4; j++) acc[i][j] = (f4v){0.f, 0.f, 0.f, 0.f};

  for (int k0 = 0; k0 < K; k0 += 32) {
#pragma unroll
    for (int i = 0; i < 2; i++) {
      int off = i * 2048 + w * 512 + lane * 8;  // element offset within tile
      int row = off >> 5, col = off & 31;
      GLDS16(A + (size_t)(m0 + row) * K + k0 + col, &As[i * 2048 + w * 512]);
      GLDS16(Bw + (size_t)(n0 + row) * K + k0 + col, &Bs[i * 2048 + w * 512]);
    }
    __syncthreads();
    s8v af[4], bf[4];
#pragma unroll
    for (int mi = 0; mi < 4; mi++)
      af[mi] = *(const s8v*)&As[(wr * 64 + mi * 16 + lc) * 32 + lg * 8];
#pragma unroll
    for (int ni = 0; ni < 4; ni++)
      bf[ni] = *(const s8v*)&Bs[(wc * 64 + ni * 16 + lc) * 32 + lg * 8];
#pragma unroll
    for (int mi = 0; mi < 4; mi++)
#pragma unroll
      for (int ni = 0; ni < 4; ni++)
        acc[mi][ni] = __builtin_amdgcn_mfma_f32_16x16x32_bf16(
            af[mi], bf[ni], acc[mi][ni], 0, 0, 0);
    __syncthreads();
  }

#pragma unroll
  for (int mi = 0; mi < 4; mi++) {
#pragma unroll
    for (int ni = 0; ni < 4; ni++) {
      int col = n0 + wc * 64 + ni * 16 + lc;
#pragma unroll
      for (int r = 0; r < 4; r++) {
        int row = m0 + wr * 64 + mi * 16 + lg * 4 + r;
        float v = acc[mi][ni][r];
        if (MODE == 0) {
          int bidx = row >> 11, t = row & 2047;
          if (col < CDIM) {
            v += bias0[col];
            v = fmaxf(v, 0.f);
            out0[(((size_t)bidx * HN + (col >> 6)) * TDIM + t) * DKD + (col & 63)] =
                f2bf(v);
          } else {
            int c2 = col - CDIM;
            v += bias1[c2];
            out1[(((size_t)bidx * HN + (c2 >> 6)) * DKD + (c2 & 63)) * TDIM + t] =
                f2bf(v);
          }
        } else {
          v += bias0[col];
          outf[(size_t)row * N + col] = v;
        }
      }
    }
  }
}

// ---------------- flash synthesizer attention ----------------
// grid: (qt=T/64, bh=B*H); block 256 = 4 waves x 16 q-rows each
__global__ __launch_bounds__(256) void attn(
    const short* __restrict__ R, const short* __restrict__ Vt,
    const short* __restrict__ W2t, const float* __restrict__ b2,
    short* __restrict__ Y) {
  __shared__ __align__(16) short plds[4][1024];  // per-wave 16x64 bf16 P staging
  const int qt = blockIdx.x, bh = blockIdx.y;
  const int b = bh >> 4, h = bh & 15;
  const int q0 = qt * 64;
  const int tid = threadIdx.x;
  const int w = tid >> 6, lane = tid & 63, lg = lane >> 4, lc = lane & 15;
  short* pl = plds[w];

  // Q (relu_out) A-fragments: 16 rows per wave, K-dim = 64
  const short* Rq = R + ((size_t)bh * TDIM + q0 + w * 16 + lc) * DKD;
  s8v rq0 = *(const s8v*)(Rq + lg * 8);
  s8v rq1 = *(const s8v*)(Rq + 32 + lg * 8);

  float m[4], l[4];
  f4v o[4];
#pragma unroll
  for (int r = 0; r < 4; r++) { m[r] = -3.0e38f; l[r] = 0.f; }
#pragma unroll
  for (int dt = 0; dt < 4; dt++) o[dt] = (f4v){0.f, 0.f, 0.f, 0.f};

  const int qrow_base = q0 + w * 16 + lg * 4;

  for (int k0 = 0; k0 <= q0; k0 += 64) {
    // ---- S = Rq @ w2[:, k0:k0+64] ----
    f4v s[4];
#pragma unroll
    for (int ct = 0; ct < 4; ct++) {
      const short* w2r = W2t + (size_t)(k0 + ct * 16 + lc) * DKD + lg * 8;
      s8v b0 = *(const s8v*)(w2r);
      s8v b1 = *(const s8v*)(w2r + 32);
      f4v z = (f4v){0.f, 0.f, 0.f, 0.f};
      z = __builtin_amdgcn_mfma_f32_16x16x32_bf16(rq0, b0, z, 0, 0, 0);
      z = __builtin_amdgcn_mfma_f32_16x16x32_bf16(rq1, b1, z, 0, 0, 0);
      s[ct] = z;
    }
    // bias + causal mask (only diagonal tile needs masking)
#pragma unroll
    for (int ct = 0; ct < 4; ct++) {
      int kcol = k0 + ct * 16 + lc;
      float bb = b2[kcol];
#pragma unroll
      for (int r = 0; r < 4; r++) {
        float v = s[ct][r] + bb;
        if (k0 == q0 && kcol > qrow_base + r) v = -1e10f;
        s[ct][r] = v;
      }
    }
    // ---- online softmax ----
    float pm[4];
#pragma unroll
    for (int r = 0; r < 4; r++)
      pm[r] = fmaxf(fmaxf(s[0][r], s[1][r]), fmaxf(s[2][r], s[3][r]));
#pragma unroll
    for (int off = 1; off < 16; off <<= 1) {
#pragma unroll
      for (int r = 0; r < 4; r++) pm[r] = fmaxf(pm[r], __shfl_xor(pm[r], off));
    }
    float sc[4], rs[4];
#pragma unroll
    for (int r = 0; r < 4; r++) {
      float nm = fmaxf(m[r], pm[r]);
      sc[r] = __expf(m[r] - nm);
      m[r] = nm;
      rs[r] = 0.f;
    }
#pragma unroll
    for (int ct = 0; ct < 4; ct++)
#pragma unroll
      for (int r = 0; r < 4; r++) {
        float p = __expf(s[ct][r] - m[r]);
        s[ct][r] = p;
        rs[r] += p;
      }
#pragma unroll
    for (int off = 1; off < 16; off <<= 1) {
#pragma unroll
      for (int r = 0; r < 4; r++) rs[r] += __shfl_xor(rs[r], off);
    }
#pragma unroll
    for (int r = 0; r < 4; r++) l[r] = l[r] * sc[r] + rs[r];
#pragma unroll
    for (int dt = 0; dt < 4; dt++) {
      f4v t = o[dt];
#pragma unroll
      for (int r = 0; r < 4; r++) t[r] *= sc[r];
      o[dt] = t;
    }
    // ---- P (C-layout) -> LDS bf16 (XOR-swizzled) -> A-fragments ----
#pragma unroll
    for (int ct = 0; ct < 4; ct++) {
#pragma unroll
      for (int r = 0; r < 4; r++) {
        int row = lg * 4 + r, col = ct * 16 + lc;
        int ba = (row * 128 + col * 2) ^ ((row & 7) << 4);
        *(short*)((char*)pl + ba) = f2bf(s[ct][r]);
      }
    }
    s8v pa0, pa1;
    {
      int lr = lc;
      int b0a = (lr * 128 + lg * 16) ^ ((lr & 7) << 4);
      int b1a = (lr * 128 + lg * 16 + 64) ^ ((lr & 7) << 4);
      pa0 = *(const s8v*)((char*)pl + b0a);
      pa1 = *(const s8v*)((char*)pl + b1a);
    }
    // ---- O += P @ V (V^T rows are contiguous in Vt) ----
#pragma unroll
    for (int dt = 0; dt < 4; dt++) {
      const short* vr = Vt + ((size_t)bh * DKD + dt * 16 + lc) * TDIM + k0 + lg * 8;
      s8v v0 = *(const s8v*)(vr);
      s8v v1 = *(const s8v*)(vr + 32);
      o[dt] = __builtin_amdgcn_mfma_f32_16x16x32_bf16(pa0, v0, o[dt], 0, 0, 0);
      o[dt] = __builtin_amdgcn_mfma_f32_16x16x32_bf16(pa1, v1, o[dt], 0, 0, 0);
    }
  }
  // ---- epilogue: O/l -> Y (B,T,C) bf16 ----
#pragma unroll
  for (int dt = 0; dt < 4; dt++) {
#pragma unroll
    for (int r = 0; r < 4; r++) {
      float y = o[dt][r] / l[r];
      int qrow = qrow_base + r;
      Y[((size_t)b * TDIM + qrow) * CDIM + h * DKD + dt * 16 + lc] = f2bf(y);
    }
  }
}

// ---------------- launch ----------------
extern "C" void kernel_launch(void* const* d_in, const int* in_sizes, int n_in,
                              void* d_out, int out_size, void* d_ws, size_t ws_size,
                              hipStream_t stream) {
  const float* x     = (const float*)d_in[0];
  const float* w1w   = (const float*)d_in[1];
  const float* w1b   = (const float*)d_in[2];
  const float* w2    = (const float*)d_in[3];
  const float* b2    = (const float*)d_in[4];
  const float* valw  = (const float*)d_in[5];
  const float* valb  = (const float*)d_in[6];
  const float* projw = (const float*)d_in[7];
  const float* projb = (const float*)d_in[8];

  char* ws = (char*)d_ws;
  short* xb  = (short*)(ws);               // x bf16:      4096x1024 (8 MB)
  short* wb  = (short*)(ws + (8u << 20));  // [w1;val]:    2048x1024 (4 MB)
  short* pj  = (short*)(ws + (12u << 20)); // proj bf16:   1024x1024 (2 MB)
  short* w2t = (short*)(ws + (14u << 20)); // w2^T bf16:   2048x64   (256 KB)
  short* Rb  = (short*)(ws + (16u << 20)); // relu_out:    (32,2048,64) (8 MB)
  short* Vt  = (short*)(ws + (24u << 20)); // V transposed:(32,64,2048) (8 MB)
  short* Yb  = (short*)(ws + (32u << 20)); // attn out:    4096x1024 (8 MB)

  cvt4<<<4096, 256, 0, stream>>>(x, xb, 4194304);
  cvt4<<<1024, 256, 0, stream>>>(w1w, wb, 1048576);
  cvt4<<<1024, 256, 0, stream>>>(valw, wb + 1048576, 1048576);
  cvt4<<<1024, 256, 0, stream>>>(projw, pj, 1048576);
  w2_transpose<<<32, 256, 0, stream>>>(w2, w2t);

  // h1/v fused GEMM: M=4096, N=2048 (cols 0..1023 relu->R, 1024..2047 ->Vt)
  gemm_bt<0><<<dim3(16, 32), 256, 0, stream>>>(xb, wb, w1b, valb, Rb, Vt,
                                               nullptr, 4096, 2048, 1024);
  // flash synthesizer attention
  attn<<<dim3(32, 32), 256, 0, stream>>>(Rb, Vt, w2t, b2, Yb);
  // output projection: M=4096, N=1024, fp32 out
  gemm_bt<1><<<dim3(8, 32), 256, 0, stream>>>(Yb, pj, projb, nullptr, nullptr,
                                              nullptr, (float*)d_out, 4096,
                                              1024, 1024);
}

// Round 7
// 299.194 us; speedup vs baseline: 1.3318x; 1.3318x over previous
//
#include <hip/hip_runtime.h>
#include <hip/hip_bf16.h>
#include <cstdint>
#include <cstddef>

// Problem constants
#define BATCH 2
#define TDIM 2048
#define CDIM 1024
#define HN 16
#define DKD 64

typedef __attribute__((ext_vector_type(8))) short s8v;   // 8 bf16 (4 VGPR)
typedef __attribute__((ext_vector_type(4))) short s4v;
typedef __attribute__((ext_vector_type(4))) float f4v;   // 16x16 MFMA accum
typedef __attribute__((ext_vector_type(16))) float f16v; // 32x32 MFMA accum

__device__ __forceinline__ short f2bf(float f) {
  unsigned u = __float_as_uint(f);
  unsigned r = u + 0x7fffu + ((u >> 16) & 1u);  // round-nearest-even
  return (short)(r >> 16);
}

__device__ __forceinline__ unsigned cvtpk_bf16(float lo, float hi) {
  unsigned r;
  asm("v_cvt_pk_bf16_f32 %0, %1, %2" : "=v"(r) : "v"(lo), "v"(hi));
  return r;
}

// v_permlane32_swap_b32: a.hi32lanes <-> b.lo32lanes
__device__ __forceinline__ void plswap(unsigned& a, unsigned& b) {
  asm volatile("v_permlane32_swap_b32 %0, %1" : "+v"(a), "+v"(b));
}

__device__ __forceinline__ f16v fzero16() {
  f16v z;
#pragma unroll
  for (int i = 0; i < 16; i++) z[i] = 0.f;
  return z;
}

#define GLDS16(g, l)                                                         \
  __builtin_amdgcn_global_load_lds(                                          \
      (const __attribute__((address_space(1))) unsigned*)(g),                \
      (__attribute__((address_space(3))) unsigned*)(l), 16, 0, 0)

// ---------------- conversions ----------------
__global__ void cvt4(const float* __restrict__ s, short* __restrict__ d, int n) {
  int i = (blockIdx.x * 256 + threadIdx.x) * 4;
  if (i >= n) return;
  const float4 v = *(const float4*)(s + i);
  s4v o;
  o[0] = f2bf(v.x); o[1] = f2bf(v.y); o[2] = f2bf(v.z); o[3] = f2bf(v.w);
  *(s4v*)(d + i) = o;
}

// w2 (64 x 2048) fp32 -> w2t (2048 x 64) bf16
__global__ void w2_transpose(const float* __restrict__ s, short* __restrict__ d) {
  __shared__ float tile[64][65];
  int k0 = blockIdx.x * 64;
  for (int i = threadIdx.x; i < 64 * 64; i += 256) {
    int r = i >> 6, c = i & 63;
    tile[r][c] = s[(size_t)r * 2048 + k0 + c];
  }
  __syncthreads();
  for (int i = threadIdx.x; i < 64 * 64; i += 256) {
    int kk = i >> 6, dd = i & 63;
    d[(size_t)(k0 + kk) * 64 + dd] = f2bf(tile[dd][kk]);
  }
}

// ---------------- GEMM (A row-major MxK, B row-major NxK i.e. B^T input) ----
// MODE 0: N=2048 fused epilogue -> relu+bias into R[(b,h),t,d], bias into Vt[(b,h),d,t]
// MODE 1: N=1024 bias epilogue -> fp32 out
template <int MODE>
__global__ __launch_bounds__(256) void gemm_bt(
    const short* __restrict__ A, const short* __restrict__ Bw,
    const float* __restrict__ bias0, const float* __restrict__ bias1,
    short* __restrict__ out0, short* __restrict__ out1,
    float* __restrict__ outf, int M, int N, int K) {
  __shared__ __align__(16) short As[128 * 32];
  __shared__ __align__(16) short Bs[128 * 32];
  const int tid = threadIdx.x;
  const int w = tid >> 6, lane = tid & 63, lg = lane >> 4, lc = lane & 15;
  const int m0 = blockIdx.y * 128, n0 = blockIdx.x * 128;
  const int wr = w >> 1, wc = w & 1;

  f4v acc[4][4];
#pragma unroll
  for (int i = 0; i < 4; i++)
#pragma unroll
    for (int j = 0; j < 4; j++) acc[i][j] = (f4v){0.f, 0.f, 0.f, 0.f};

  for (int k0 = 0; k0 < K; k0 += 32) {
#pragma unroll
    for (int i = 0; i < 2; i++) {
      int off = i * 2048 + w * 512 + lane * 8;  // element offset within tile
      int row = off >> 5, col = off & 31;
      GLDS16(A + (size_t)(m0 + row) * K + k0 + col, &As[i * 2048 + w * 512]);
      GLDS16(Bw + (size_t)(n0 + row) * K + k0 + col, &Bs[i * 2048 + w * 512]);
    }
    __syncthreads();
    s8v af[4], bf[4];
#pragma unroll
    for (int mi = 0; mi < 4; mi++)
      af[mi] = *(const s8v*)&As[(wr * 64 + mi * 16 + lc) * 32 + lg * 8];
#pragma unroll
    for (int ni = 0; ni < 4; ni++)
      bf[ni] = *(const s8v*)&Bs[(wc * 64 + ni * 16 + lc) * 32 + lg * 8];
#pragma unroll
    for (int mi = 0; mi < 4; mi++)
#pragma unroll
      for (int ni = 0; ni < 4; ni++)
        acc[mi][ni] = __builtin_amdgcn_mfma_f32_16x16x32_bf16(
            af[mi], bf[ni], acc[mi][ni], 0, 0, 0);
    __syncthreads();
  }

#pragma unroll
  for (int mi = 0; mi < 4; mi++) {
#pragma unroll
    for (int ni = 0; ni < 4; ni++) {
      int col = n0 + wc * 64 + ni * 16 + lc;
#pragma unroll
      for (int r = 0; r < 4; r++) {
        int row = m0 + wr * 64 + mi * 16 + lg * 4 + r;
        float v = acc[mi][ni][r];
        if (MODE == 0) {
          int bidx = row >> 11, t = row & 2047;
          if (col < CDIM) {
            v += bias0[col];
            v = fmaxf(v, 0.f);
            out0[(((size_t)bidx * HN + (col >> 6)) * TDIM + t) * DKD + (col & 63)] =
                f2bf(v);
          } else {
            int c2 = col - CDIM;
            v += bias1[c2];
            out1[(((size_t)bidx * HN + (c2 >> 6)) * DKD + (c2 & 63)) * TDIM + t] =
                f2bf(v);
          }
        } else {
          v += bias0[col];
          outf[(size_t)row * N + col] = v;
        }
      }
    }
  }
}

// ---------------- flash synthesizer attention, swapped-operand 32x32 ------
// grid: (T/32 [reversed], B*H); block = 64 (one wave, 32 q-rows).
// All MFMA fragments are direct 16B global row-reads: no LDS, no shfl trees.
// S^T = mfma(w2t_frag, R_frag): lane holds S[k(16 regs + partner), q=lane&31].
// P -> bf16 A-frags via v_cvt_pk_bf16_f32 + v_permlane32_swap_b32 (T12).
// O = mfma(P_frag, Vt_frag): C rows = q, cols = d.
__global__ __launch_bounds__(64) void attn(
    const short* __restrict__ R, const short* __restrict__ Vt,
    const short* __restrict__ W2t, const float* __restrict__ b2,
    short* __restrict__ Y) {
  const int lane = threadIdx.x;
  const int qr = lane & 31, hi = lane >> 5;
  const int qt = gridDim.x - 1 - blockIdx.x;  // heavy (high-qt) blocks first
  const int bh = blockIdx.y;
  const int b = bh >> 4, h = bh & 15;
  const int q0 = qt * 32;
  const int q = q0 + qr;
  const int nt = qt + 1;  // number of 32-wide k tiles

  // R B-fragments (loop-invariant): lane holds R[q][d0*16 + hi*8 + e]
  const short* Rrow = R + ((size_t)bh * TDIM + q) * DKD + hi * 8;
  s8v rq[4];
#pragma unroll
  for (int i = 0; i < 4; i++) rq[i] = *(const s8v*)(Rrow + 16 * i);

  const short* Vb = Vt + (size_t)bh * DKD * TDIM;

  f16v o0 = fzero16(), o1 = fzero16();
  float m = -1e30f, l = 0.f;

  // preload w2 A-frags for tile 0: lane holds w2t[k0+qr][d0*16 + hi*8 + e]
  s8v wf[4];
#pragma unroll
  for (int i = 0; i < 4; i++)
    wf[i] = *(const s8v*)(W2t + (size_t)qr * DKD + i * 16 + hi * 8);

  for (int t = 0; t < nt; ++t) {
    const int k0 = t * 32;
    // V B-frags for this tile (needed late -> latency hides under softmax)
    s8v vf[4];
#pragma unroll
    for (int dh = 0; dh < 2; ++dh)
#pragma unroll
      for (int kh = 0; kh < 2; ++kh)
        vf[dh * 2 + kh] =
            *(const s8v*)(Vb + (size_t)(dh * 32 + qr) * TDIM + k0 + kh * 16 + hi * 8);

    // S^T = w2tile @ R^T : reg r holds S[k0 + (r&3)+8*(r>>2)+4*hi, q]
    f16v sacc = fzero16();
#pragma unroll
    for (int i = 0; i < 4; i++)
      sacc = __builtin_amdgcn_mfma_f32_32x32x16_bf16(wf[i], rq[i], sacc, 0, 0, 0);

    // prefetch next tile's w2 frags
    s8v wfn[4];
    if (t + 1 < nt) {
#pragma unroll
      for (int i = 0; i < 4; i++)
        wfn[i] = *(const s8v*)(W2t + (size_t)(k0 + 32 + qr) * DKD + i * 16 + hi * 8);
    }

    // bias b2[k]
    float s[16];
#pragma unroll
    for (int j = 0; j < 4; ++j) {
      const float4 bb = *(const float4*)(b2 + k0 + 4 * hi + 8 * j);
      s[4 * j + 0] = sacc[4 * j + 0] + bb.x;
      s[4 * j + 1] = sacc[4 * j + 1] + bb.y;
      s[4 * j + 2] = sacc[4 * j + 2] + bb.z;
      s[4 * j + 3] = sacc[4 * j + 3] + bb.w;
    }
    // causal mask (diagonal tile only)
    if (k0 == q0) {
#pragma unroll
      for (int r = 0; r < 16; ++r) {
        int kl = (r & 3) + 8 * (r >> 2) + 4 * hi;
        if (kl > qr) s[r] = -1e10f;
      }
    }

    // tile max (15 in-reg fmax + 1 half-swap)
    float pm = s[0];
#pragma unroll
    for (int r = 1; r < 16; ++r) pm = fmaxf(pm, s[r]);
    pm = fmaxf(pm, __shfl_xor(pm, 32));

    // deferred rescale (T13): rare after tile 0 (scores are tiny)
    if (__any(pm > m + 8.0f)) {
      float nm = fmaxf(m, pm);
      float sc = __expf(m - nm);  // tile 0: exp(-huge) = 0 -> clean init
#pragma unroll
      for (int r = 0; r < 16; ++r) {
        float scr = __shfl(sc, (r & 3) + 8 * (r >> 2) + 4 * hi);
        o0[r] *= scr;
        o1[r] *= scr;
      }
      l *= sc;
      m = nm;
    }

    // P = exp(S - m), row-sum
    float pv[16], ts = 0.f;
#pragma unroll
    for (int r = 0; r < 16; ++r) {
      pv[r] = __expf(s[r] - m);
      ts += pv[r];
    }
    ts += __shfl_xor(ts, 32);
    l += ts;

    // P -> bf16 A-fragments: 8 cvt_pk + 4 permlane32_swap
    unsigned c[8];
#pragma unroll
    for (int j = 0; j < 8; ++j) c[j] = cvtpk_bf16(pv[2 * j], pv[2 * j + 1]);
    plswap(c[0], c[2]);
    plswap(c[1], c[3]);
    plswap(c[4], c[6]);
    plswap(c[5], c[7]);
    union { unsigned u[4]; s8v v; } pa0, pa1;
    pa0.u[0] = c[0]; pa0.u[1] = c[1]; pa0.u[2] = c[2]; pa0.u[3] = c[3];
    pa1.u[0] = c[4]; pa1.u[1] = c[5]; pa1.u[2] = c[6]; pa1.u[3] = c[7];

    // O += P @ V
    o0 = __builtin_amdgcn_mfma_f32_32x32x16_bf16(pa0.v, vf[0], o0, 0, 0, 0);
    o0 = __builtin_amdgcn_mfma_f32_32x32x16_bf16(pa1.v, vf[1], o0, 0, 0, 0);
    o1 = __builtin_amdgcn_mfma_f32_32x32x16_bf16(pa0.v, vf[2], o1, 0, 0, 0);
    o1 = __builtin_amdgcn_mfma_f32_32x32x16_bf16(pa1.v, vf[3], o1, 0, 0, 0);

#pragma unroll
    for (int i = 0; i < 4; i++) wf[i] = wfn[i];
  }

  // epilogue: O/l -> Y (B,T,C) bf16. C layout: col=d=lane&31, row=q per reg.
  const float linv = 1.0f / l;
#pragma unroll
  for (int r = 0; r < 16; ++r) {
    int ql = (r & 3) + 8 * (r >> 2) + 4 * hi;
    float li = __shfl(linv, ql);
    size_t base = ((size_t)b * TDIM + q0 + ql) * CDIM + h * DKD;
    Y[base + qr] = f2bf(o0[r] * li);
    Y[base + 32 + qr] = f2bf(o1[r] * li);
  }
}

// ---------------- launch ----------------
extern "C" void kernel_launch(void* const* d_in, const int* in_sizes, int n_in,
                              void* d_out, int out_size, void* d_ws, size_t ws_size,
                              hipStream_t stream) {
  const float* x     = (const float*)d_in[0];
  const float* w1w   = (const float*)d_in[1];
  const float* w1b   = (const float*)d_in[2];
  const float* w2    = (const float*)d_in[3];
  const float* b2    = (const float*)d_in[4];
  const float* valw  = (const float*)d_in[5];
  const float* valb  = (const float*)d_in[6];
  const float* projw = (const float*)d_in[7];
  const float* projb = (const float*)d_in[8];

  char* ws = (char*)d_ws;
  short* xb  = (short*)(ws);               // x bf16:      4096x1024 (8 MB)
  short* wb  = (short*)(ws + (8u << 20));  // [w1;val]:    2048x1024 (4 MB)
  short* pj  = (short*)(ws + (12u << 20)); // proj bf16:   1024x1024 (2 MB)
  short* w2t = (short*)(ws + (14u << 20)); // w2^T bf16:   2048x64   (256 KB)
  short* Rb  = (short*)(ws + (16u << 20)); // relu_out:    (32,2048,64) (8 MB)
  short* Vt  = (short*)(ws + (24u << 20)); // V transposed:(32,64,2048) (8 MB)
  short* Yb  = (short*)(ws + (32u << 20)); // attn out:    4096x1024 (8 MB)

  cvt4<<<4096, 256, 0, stream>>>(x, xb, 4194304);
  cvt4<<<1024, 256, 0, stream>>>(w1w, wb, 1048576);
  cvt4<<<1024, 256, 0, stream>>>(valw, wb + 1048576, 1048576);
  cvt4<<<1024, 256, 0, stream>>>(projw, pj, 1048576);
  w2_transpose<<<32, 256, 0, stream>>>(w2, w2t);

  // h1/v fused GEMM: M=4096, N=2048 (cols 0..1023 relu->R, 1024..2047 ->Vt)
  gemm_bt<0><<<dim3(16, 32), 256, 0, stream>>>(xb, wb, w1b, valb, Rb, Vt,
                                               nullptr, 4096, 2048, 1024);
  // flash synthesizer attention (1 wave / 32 q-rows per block, qt reversed)
  attn<<<dim3(64, 32), 64, 0, stream>>>(Rb, Vt, w2t, b2, Yb);
  // output projection: M=4096, N=1024, fp32 out
  gemm_bt<1><<<dim3(8, 32), 256, 0, stream>>>(Yb, pj, projb, nullptr, nullptr,
                                              nullptr, (float*)d_out, 4096,
                                              1024, 1024);
}